// Round 7
// baseline (1295.800 us; speedup 1.0000x reference)
//
#include <hip/hip_runtime.h>
#include <hip/hip_bf16.h>

#define T_STEPS 20
#define NSTEP   19
#define NN      192
#define DH      64
#define DE      32

// ---------------- workspace float offsets (R6 layout kept) ----------------
enum : int {
  O_H     = 0,                 // (unused in persistent version; layout kept)
  O_C     = O_H    + NN*DH,
  O_UH0   = O_C    + NN*DH,    // [N][64] float2 {U20, HW0}  — BYPASS-ONLY access
  O_UH1   = O_UH0  + 2*NN*DH,  // [N][64] float2 {U21, HW1}  — BYPASS-ONLY access
  O_CW    = O_UH1  + 2*NN*DH,  // (unused)
  O_OG    = O_CW   + NN*DH,    // (unused)
  O_U1    = O_OG   + NN*DH,    // (unused)
  O_S1    = O_U1   + NN*DH,    // (unused)
  O_S20   = O_S1   + NN,       // BYPASS-ONLY
  O_S21   = O_S20  + NN,       // BYPASS-ONLY
  O_ACC   = O_S21  + NN,       // [19][4] atomics; bypass readback at finalize
  O_GBAR  = O_ACC  + NSTEP*4,  // {arrive_cnt, release_flag}
  O_WIHT  = O_GBAR + 4,        // [e][G] 8192  (zero region ends here)
  O_WHHT  = O_WIHT + 8192,     // [k][G] 16384
  O_BIH   = O_WHHT + 16384,
  O_WIN   = O_BIH  + 256,
  O_BIN   = O_WIN  + 64,
  O_WRELF = O_BIN  + 32,       // 128  [p][d][c]
  O_BRELF = O_WRELF+ 128,
  O_WGR   = O_BRELF+ 64,       // 4096 [p][d][h]  (transposed)
  O_WGH1T = O_WGR  + 4096,     // 8192 [p][k][h]
  O_WGH2T = O_WGH1T+ 8192,
  O_BGATE = O_WGH2T+ 8192,     // contiguous small-const region cB:
  O_WARR  = O_BGATE+ 128,      //   BGATE 128, WARR 64, WARH1 128, WARH2 128, BAR 4
  O_WARH1 = O_WARR + 64,
  O_WARH2 = O_WARH1+ 128,
  O_BAR   = O_WARH2+ 128,
  O_WNEIT = O_BAR  + 4,        // 8192 [p][k][h]
  O_WOUT  = O_WNEIT+ 8192,     // cC: WOUT 128, BOUT 2
  O_BOUT  = O_WOUT + 128,
  O_ISF   = O_BOUT + 2,
  O_TOTAL = O_ISF  + 1
};

typedef unsigned long long ull;

__device__ __forceinline__ float bf2f(__hip_bfloat16 v) { return __bfloat162float(v); }
__device__ __forceinline__ float sigm(float x) { return 1.0f / (1.0f + __expf(-x)); }
__device__ __forceinline__ float tanh_fast(float x) {
  float e = __expf(-2.0f * fabsf(x));
  float r = (1.0f - e) / (1.0f + e);
  return copysignf(r, x);
}

__device__ __forceinline__ float ldf(const void* p, int idx, int isf32) {
  if (isf32) return ((const float*)p)[idx];
  return bf2f(((const __hip_bfloat16*)p)[idx]);
}
__device__ __forceinline__ void stf(void* p, int idx, float v, int isf32) {
  if (isf32) ((float*)p)[idx] = v;
  else       ((__hip_bfloat16*)p)[idx] = __float2bfloat16(v);
}

// -------- cache-bypass (sc0 sc1) plain loads/stores: coherent at the device
// coherence point, never allocate/consult L1/L2. Async variants must be
// followed by vm_wait0() before their results are consumed (rule #18:
// sched_barrier after the waitcnt prevents register-use hoisting).
__device__ __forceinline__ ull ld_coh_u64_async(const void* p) {
  ull v;
  asm volatile("global_load_dwordx2 %0, %1, off sc0 sc1" : "=v"(v) : "v"(p));
  return v;
}
__device__ __forceinline__ float ld_coh_f32_async(const void* p) {
  float v;
  asm volatile("global_load_dword %0, %1, off sc0 sc1" : "=v"(v) : "v"(p));
  return v;
}
__device__ __forceinline__ float ld_coh_f32(const void* p) {   // completed
  float v;
  asm volatile("global_load_dword %0, %1, off sc0 sc1\n\ts_waitcnt vmcnt(0)"
               : "=v"(v) : "v"(p) : "memory");
  return v;
}
__device__ __forceinline__ unsigned ld_coh_u32(const void* p) { // completed
  unsigned v;
  asm volatile("global_load_dword %0, %1, off sc0 sc1\n\ts_waitcnt vmcnt(0)"
               : "=v"(v) : "v"(p) : "memory");
  return v;
}
__device__ __forceinline__ void st_coh_f32(void* p, float v) {
  asm volatile("global_store_dword %0, %1, off sc0 sc1" :: "v"(p), "v"(v) : "memory");
}
__device__ __forceinline__ void st_coh_u32(void* p, unsigned v) {
  asm volatile("global_store_dword %0, %1, off sc0 sc1" :: "v"(p), "v"(v) : "memory");
}
__device__ __forceinline__ void vm_wait0() {
  asm volatile("s_waitcnt vmcnt(0)" ::: "memory");
  __builtin_amdgcn_sched_barrier(0);
}

// Fence-free grid barrier (concept proven correct in R3). All cross-block
// data moves via sc0sc1 bypass ops (at coherence point once vmcnt==0), so NO
// threadfence (no wbL2/inv) is needed — L2 stays hot forever. 192 blocks,
// plain launch, all co-resident (proven R2/R3/R6).
__device__ __forceinline__ void gridbar(float* F, unsigned ep) {
  asm volatile("s_waitcnt vmcnt(0)" ::: "memory");  // my bypass stores are at CP
  __syncthreads();
  if (threadIdx.x == 0) {
    unsigned* bar = (unsigned*)(F + O_GBAR);
    unsigned v = atomicAdd(bar, 1u) + 1u;           // device-scope, fabric (m20)
    if (v == (ep + 1u) * (unsigned)NN) {
      st_coh_u32(bar + 1, ep + 1u);
    } else {
      while (ld_coh_u32(bar + 1) < ep + 1u) __builtin_amdgcn_s_sleep(2);
    }
  }
  __syncthreads();
}

// ---------------- init: detect dtype, zero state, convert/transpose weights ----
__global__ __launch_bounds__(256) void k_init(float* __restrict__ F,
                       void* __restrict__ out,
                       const void* w_in,  const void* b_in,
                       const void* w_ih,  const void* w_hh,
                       const void* b_ih,  const void* b_hh,
                       const void* w_rel, const void* b_rel,
                       const void* w_gate,const void* b_gate,
                       const void* w_ar,  const void* b_ar,
                       const void* w_nei, const void* w_out,
                       const void* b_out, int isf_arg) {
  __shared__ int s_isf;
  const int wave = threadIdx.x >> 6, lane = threadIdx.x & 63;
  if (isf_arg >= 0) {
    if (threadIdx.x == 0) s_isf = isf_arg;
  } else if (wave == 0) {
    // dtype detect fallback (proven r3-r9)
    const unsigned short* u = (const unsigned short*)w_gate;
    int bad = 0;
    for (int x = lane; x < 1024; x += 64) {
      float v = __uint_as_float(((unsigned)u[x]) << 16);
      if (!(fabsf(v) <= 4.0f)) bad++;
    }
    for (int o = 32; o >= 1; o >>= 1) bad += __shfl_xor(bad, o, 64);
    if (lane == 0) s_isf = (bad > 64);
  }
  __syncthreads();
  const int isf32 = s_isf;
  if (blockIdx.x == 0 && threadIdx.x == 0) F[O_ISF] = (float)isf32;

  int tid = blockIdx.x * blockDim.x + threadIdx.x;
  int stride = gridDim.x * blockDim.x;
  for (int x = tid; x < O_WIHT; x += stride) F[x] = 0.f;   // incl. UH/S2/ACC/GBAR
  for (int x = tid; x < NN*2;  x += stride) stf(out, (T_STEPS-1)*NN*2 + x, 0.f, isf32);
  for (int x = tid; x < 8192;  x += stride) { int e = x >> 8, G = x & 255; F[O_WIHT + x] = ldf(w_ih, G*32 + e, isf32); }
  for (int x = tid; x < 16384; x += stride) { int k = x >> 8, G = x & 255; F[O_WHHT + x] = ldf(w_hh, G*64 + k, isf32); }
  for (int x = tid; x < 256;   x += stride) F[O_BIH + x] = ldf(b_ih, x, isf32) + ldf(b_hh, x, isf32);
  for (int x = tid; x < 64;    x += stride) F[O_WIN + x] = ldf(w_in, x, isf32);
  for (int x = tid; x < 32;    x += stride) F[O_BIN + x] = ldf(b_in, x, isf32);
  for (int x = tid; x < 128;   x += stride) F[O_WRELF + x] = ldf(w_rel, x, isf32);
  for (int x = tid; x < 64;    x += stride) F[O_BRELF + x] = ldf(b_rel, x, isf32);
  // WGR transposed [p][d][h] for conflict-free LDS staging + reads
  for (int x = tid; x < 4096;  x += stride) { int p = x >> 11, d = (x >> 6) & 31, h = x & 63;
    F[O_WGR + x] = ldf(w_gate, p*10240 + h*160 + d, isf32); }
  for (int x = tid; x < 8192;  x += stride) { int p = x >> 12, k = (x >> 6) & 63, h = x & 63;
    F[O_WGH1T + x] = ldf(w_gate, p*10240 + h*160 + 32 + k, isf32); }
  for (int x = tid; x < 8192;  x += stride) { int p = x >> 12, k = (x >> 6) & 63, h = x & 63;
    F[O_WGH2T + x] = ldf(w_gate, p*10240 + h*160 + 96 + k, isf32); }
  for (int x = tid; x < 128;   x += stride) F[O_BGATE + x] = ldf(b_gate, x, isf32);
  for (int x = tid; x < 64;    x += stride) { int p = x >> 5, d = x & 31; F[O_WARR + x] = ldf(w_ar, p*160 + d, isf32); }
  for (int x = tid; x < 128;   x += stride) { int p = x >> 6, k = x & 63; F[O_WARH1 + x] = ldf(w_ar, p*160 + 32 + k, isf32); }
  for (int x = tid; x < 128;   x += stride) { int p = x >> 6, k = x & 63; F[O_WARH2 + x] = ldf(w_ar, p*160 + 96 + k, isf32); }
  for (int x = tid; x < 2;     x += stride) F[O_BAR + x] = ldf(b_ar, x, isf32);
  for (int x = tid; x < 8192;  x += stride) { int p = x >> 12, k = (x >> 6) & 63, h = x & 63;
    F[O_WNEIT + x] = ldf(w_nei, p*4096 + h*64 + k, isf32); }
  for (int x = tid; x < 128;   x += stride) F[O_WOUT + x] = ldf(w_out, x, isf32);
  for (int x = tid; x < 2;     x += stride) F[O_BOUT + x] = ldf(b_out, x, isf32);
}

// LSTM step t + prep for gcn p=0. Row-local state in LDS; cross-block UH0/S20
// published via bypass stores. No trailing sync (gridbar provides it).
__device__ __forceinline__ void lstm_prep(
    float* __restrict__ F, const void* __restrict__ nnorm, int isf32,
    int t, int i, int tid, int wave, int lane,
    const float* wih_r, const float* whh_r, float bih_r,
    const float* s_win, const float* s_cB,
    float* s_x, float* s_hc, float* s_cc, float* s_gates, float* s_h1,
    float* s_cw, float* s_og, float* s_u1, float* s_s1)
{
  if (wave == 1 && lane < DE) {
    float nx = ldf(nnorm, (t*NN + i)*2 + 0, isf32);
    float ny = ldf(nnorm, (t*NN + i)*2 + 1, isf32);
    s_x[lane] = fmaxf(nx*s_win[lane*2] + ny*s_win[lane*2 + 1] + s_win[64 + lane], 0.f);
  }
  __syncthreads();
  {
    float acc = bih_r;                              // gate-major G = tid
#pragma unroll
    for (int e = 0; e < DE; e++) acc += wih_r[e] * s_x[e];
#pragma unroll
    for (int k = 0; k < DH; k++) acc += whh_r[k] * s_hc[k];
    s_gates[tid] = acc;
  }
  __syncthreads();
  if (wave == 0) {
    float ig = sigm(s_gates[lane]);
    float fg = sigm(s_gates[64 + lane]);
    float gg = tanh_fast(s_gates[128 + lane]);
    float og = sigm(s_gates[192 + lane]);
    float c1 = fg * s_cc[lane] + ig * gg;
    float h1 = og * tanh_fast(c1);
    s_cw[lane] = c1;
    s_og[lane] = og;
    s_h1[lane] = h1;
    st_coh_f32(F + O_UH0 + 2*(i*DH + lane) + 1, h1);   // publish HW0 (.y)
  }
  __syncthreads();
  if (wave == 0) {
    float a = 0.f;
    const float* w = F + O_WGH1T + lane;               // p=0, L2-hot
    for (int k = 0; k < DH; k++) a += w[k*DH] * s_h1[k];
    s_u1[lane] = a;
  } else if (wave == 1) {
    float a = 0.f;
    const float* w = F + O_WGH2T + lane;               // p=0, L2-hot
    for (int k = 0; k < DH; k++) a += w[k*DH] * s_h1[k];
    st_coh_f32(F + O_UH0 + 2*(i*DH + lane), a);        // publish U20 (.x)
  } else if (wave == 2) {
    float hp = s_h1[lane];
    float a1 = hp * s_cB[192 + lane];                  // WARH1 p=0
    float a2 = hp * s_cB[320 + lane];                  // WARH2 p=0
    for (int o = 32; o >= 1; o >>= 1) { a1 += __shfl_xor(a1, o, 64); a2 += __shfl_xor(a2, o, 64); }
    if (lane == 0) { *s_s1 = a1; st_coh_f32(F + O_S20 + i, a2); }
  }
}

// ---------------- persistent kernel: 19 steps, 2 fence-free barriers/step ---
__global__ __launch_bounds__(256, 1) void k_main(float* __restrict__ F,
    const void* __restrict__ nabs, const void* __restrict__ nnorm,
    const int* __restrict__ seq, const int* __restrict__ nei,
    void* __restrict__ out, int isf_arg)
{
  __shared__ float s_rt[NN*33];                    // 24.75 KB, pad-33
  __shared__ float s_score[NN], s_pos[NN], s_neif[NN];
  __shared__ int   s_jlist[NN];
  __shared__ ull   s_cmask[3];
  __shared__ float s_red[4*DH], s_v1[4], s_msg[DH], s_hprep[DH];
  __shared__ float s_x[DE], s_hc[DH], s_cc[DH], s_gates[4*DH], s_h1[DH];
  __shared__ float s_cw[DH], s_og[DH], s_u1[DH], s_s1;
  __shared__ float s_wgt[4096];                    // 16 KB  [p][d][h]
  __shared__ float s_cA[192], s_cB[452], s_cC[130], s_win[96];
  __shared__ float s_fin[NSTEP*4];

  const int tid = threadIdx.x, wave = tid >> 6, lane = tid & 63;
  const int i = blockIdx.x;
  const int isf32 = (isf_arg >= 0) ? isf_arg : (int)F[O_ISF];

  // one-time register caches (1 block/CU, VGPR budget huge)
  float wih_r[DE], whh_r[DH];
  const float bih_r = F[O_BIH + tid];
#pragma unroll
  for (int e = 0; e < DE; e++) wih_r[e] = F[O_WIHT + e*256 + tid];
#pragma unroll
  for (int k = 0; k < DH; k++) whh_r[k] = F[O_WHHT + k*256 + tid];

  // one-time LDS staging (weights/consts; never invalidated — no fences ever)
  for (int x = tid; x < 4096; x += 256) s_wgt[x] = F[O_WGR + x];
  for (int x = tid; x < 192; x += 256) s_cA[x] = F[O_WRELF + x];
  for (int x = tid; x < 452; x += 256) s_cB[x] = F[O_BGATE + x];
  for (int x = tid; x < 130; x += 256) s_cC[x] = F[O_WOUT + x];
  for (int x = tid; x < 96;  x += 256) s_win[x] = F[O_WIN + x];
  if (wave == 0) { s_hc[lane] = 0.f; s_cc[lane] = 0.f; }
  __syncthreads();

  // t=0 LSTM (publishes UH0/S20 via bypass stores)
  lstm_prep(F, nnorm, isf32, 0, i, tid, wave, lane,
            wih_r, whh_r, bih_r, s_win, s_cB,
            s_x, s_hc, s_cc, s_gates, s_h1, s_cw, s_og, s_u1, &s_s1);

  unsigned ep = 0;
  for (int t = 0; t < NSTEP; ++t) {
    const int m_i = seq[t*NN + i] > 0;
    const int j = wave*64 + lane;

    // ---- masks + ballot j-list (pre-barrier; depends only on seq/nei, same
    // for both passes of this t). gridbar's sync makes jlist block-visible.
    ull mymask = 0; int nf = 0;
    if (wave < 3) {
      nf = m_i && (seq[t*NN + j] > 0) && (nei[(t*NN + i)*NN + j] > 0);
      s_neif[j] = nf ? 1.f : 0.f;
      mymask = __ballot(nf != 0);
      if (lane == 0) s_cmask[wave] = mymask;
    }
    __syncthreads();
    const int c0 = __popcll(s_cmask[0]), c1 = __popcll(s_cmask[1]);
    const int nv = c0 + c1 + __popcll(s_cmask[2]);
    if (wave < 3 && nf) {
      int base = (wave == 0) ? 0 : ((wave == 1) ? c0 : c0 + c1);
      ull lt = (1ull << lane) - 1ull;
      s_jlist[base + __popcll(mymask & lt)] = j;
    }

    for (int p = 0; p < 2; ++p) {
      gridbar(F, ep++);                    // peers' UH/S2 at coherence point
      const int last = (t == NSTEP - 1) && (p == 1);
      const int UHr = p ? O_UH1 : O_UH0;
      const int S2r = p ? O_S21 : O_S20;

      // ---- P1: early async S2 bypass load, r values, raw scores
      if (wave < 3) {
        float s2j = ld_coh_f32_async(F + S2r + j);
        float sc = 0.f, dot = 0.f;
        if (nf) {
          float cx = ldf(nabs, (t*NN + i)*2 + 0, isf32) - ldf(nabs, (t*NN + j)*2 + 0, isf32);
          float cy = ldf(nabs, (t*NN + i)*2 + 1, isf32) - ldf(nabs, (t*NN + j)*2 + 1, isf32);
          const float* wr = s_cA + p*64;
          const float* br = s_cA + 128 + p*32;
          const float* wa = s_cB + 128 + p*32;           // WARR
#pragma unroll
          for (int d = 0; d < 32; d++) {
            float rv = fmaxf(cx*wr[2*d] + cy*wr[2*d+1] + br[d], 0.f);
            s_rt[j*33 + d] = rv;
            dot += rv * wa[d];
          }
        }
        vm_wait0();                                      // s2j landed
        if (nf) sc = dot + s_s1 + s2j + s_cB[448 + p];   // BAR
        s_score[j] = sc;
      }
      __syncthreads();

      // ---- P2: masked softmax + (p==0) row stats (wave 0)
      if (wave == 0) {
        float n0 = s_neif[lane], n1 = s_neif[64+lane], n2 = s_neif[128+lane];
        float sc0 = s_score[lane], sc1 = s_score[64+lane], sc2 = s_score[128+lane];
        const float NEG = -3.0e38f;
        float mx = fmaxf(fmaxf(n0 > 0.f ? sc0 : NEG, n1 > 0.f ? sc1 : NEG),
                         n2 > 0.f ? sc2 : NEG);
        for (int o = 32; o >= 1; o >>= 1) mx = fmaxf(mx, __shfl_xor(mx, o, 64));
        float e0 = (n0 > 0.f) ? __expf(sc0 - mx) : 0.f;
        float e1 = (n1 > 0.f) ? __expf(sc1 - mx) : 0.f;
        float e2 = (n2 > 0.f) ? __expf(sc2 - mx) : 0.f;
        float s = e0 + e1 + e2;
        for (int o = 32; o >= 1; o >>= 1) s += __shfl_xor(s, o, 64);
        float inv = (s > 0.f) ? 1.0f / s : 0.f;
        float p0 = e0*inv, p1 = e1*inv, p2 = e2*inv;
        s_pos[lane] = p0; s_pos[64+lane] = p1; s_pos[128+lane] = p2;
        if (p == 0 && m_i) {
          float cnt = n0 + n1 + n2;
          float pm  = fmaxf(fmaxf(p0, p1), p2);
          for (int o = 32; o >= 1; o >>= 1) {
            cnt += __shfl_xor(cnt, o, 64);
            pm   = fmaxf(pm, __shfl_xor(pm, o, 64));
          }
          if (lane == 0 && cnt > 0.f) {
            atomicAdd(&F[O_ACC + t*4 + 1], cnt);
            atomicAdd(&F[O_ACC + t*4 + 2], pm);
            atomicAdd(&F[O_ACC + t*4 + 3], 1.f);
          }
        }
      }
      __syncthreads();

      // ---- P3: gates + msg over compacted list; UH via chunked bypass gather
      {
        float msg = 0.f, v1 = 0.f;
        if (m_i && nv > 0) {
          float wreg[32];
#pragma unroll
          for (int d = 0; d < 32; d++) wreg[d] = s_wgt[p*2048 + d*64 + lane];
          float basev = s_u1[lane] + s_cB[p*DH + lane];  // BGATE
          const float* UHbase = F + UHr;
          for (int c = 0; c < 6; ++c) {
            int k0 = wave + c*32;                        // kk = k0 + 4m, m<8
            if (k0 >= nv) break;
            int jv[8]; ull u[8];
#pragma unroll
            for (int m = 0; m < 8; m++) {
              int kk = k0 + 4*m;
              jv[m] = (kk < nv) ? s_jlist[kk] : 0;
              u[m] = ld_coh_u64_async(UHbase + 2*(jv[m]*DH + lane));
            }
            vm_wait0();
#pragma unroll
            for (int m = 0; m < 8; m++) {
              int kk = k0 + 4*m;
              if (kk < nv) {
                float ux = __uint_as_float((unsigned)u[m]);
                float uy = __uint_as_float((unsigned)(u[m] >> 32));
                float acc = basev + ux;
                const float* rr = &s_rt[jv[m]*33];
#pragma unroll
                for (int d = 0; d < 32; d++) acc += rr[d] * wreg[d];
                float g = sigm(acc);
                v1 += g;
                msg += s_pos[jv[m]] * g * uy;
              }
            }
          }
        }
        s_red[wave*DH + lane] = msg;
        for (int o = 32; o >= 1; o >>= 1) v1 += __shfl_xor(v1, o, 64);
        if (lane == 0) s_v1[wave] = v1;
      }
      __syncthreads();

      // ---- T1: combine partials + v1 atomic (wave 0)
      if (wave == 0) {
        s_msg[lane] = s_red[lane] + s_red[64+lane] + s_red[128+lane] + s_red[192+lane];
        if (p == 0 && m_i && lane == 0) {
          atomicAdd(&F[O_ACC + t*4 + 0], s_v1[0] + s_v1[1] + s_v1[2] + s_v1[3]);
        }
      }
      __syncthreads();

      // ---- T2: c/h update; publish (p=0) or commit-to-LDS (p=1)
      if (wave == 0) {
        float hcom, ccom = 0.f;
        if (m_i) {
          float cn = s_cw[lane];
          const float* wn = F + O_WNEIT + p*4096 + lane;  // L2-hot
          for (int k = 0; k < DH; k++) cn += s_msg[k] * wn[k*DH];
          hcom = s_og[lane] * tanh_fast(cn);
          s_cw[lane] = cn;
          ccom = cn;
        } else {
          hcom = p ? s_hprep[lane] : s_h1[lane];   // gcn identity for masked
        }
        if (p == 0) st_coh_f32(F + O_UH1 + 2*(i*DH + lane) + 1, hcom); // HW1
        s_hprep[lane] = hcom;
        if (p == 1 && m_i) { s_hc[lane] = hcom; s_cc[lane] = ccom; }
      }
      __syncthreads();

      if (p == 0) {
        // ---- PREP for p=1 from post-gcn0 h
        if (wave == 0) {
          float a = 0.f;
          const float* w = F + O_WGH1T + 4096 + lane;     // p=1, L2-hot
          for (int k = 0; k < DH; k++) a += w[k*DH] * s_hprep[k];
          s_u1[lane] = a;
        } else if (wave == 1) {
          float a = 0.f;
          const float* w = F + O_WGH2T + 4096 + lane;     // p=1, L2-hot
          for (int k = 0; k < DH; k++) a += w[k*DH] * s_hprep[k];
          st_coh_f32(F + O_UH1 + 2*(i*DH + lane), a);     // publish U21 (.x)
        } else if (wave == 2) {
          float hp = s_hprep[lane];
          float a1 = hp * s_cB[192 + DH + lane];          // WARH1 p=1
          float a2 = hp * s_cB[320 + DH + lane];          // WARH2 p=1
          for (int o = 32; o >= 1; o >>= 1) { a1 += __shfl_xor(a1, o, 64); a2 += __shfl_xor(a2, o, 64); }
          if (lane == 0) { s_s1 = a1; st_coh_f32(F + O_S21 + i, a2); }
        }
      } else {
        // ---- OUT row for step t
        if (wave == 0 && lane < 2) {
          float a = 0.f;
          if (m_i) {
            a = s_cC[128 + lane];                         // BOUT
            const float* wo = s_cC + lane*DH;             // WOUT
            for (int h = 0; h < DH; h++) a += s_hprep[h] * wo[h];
          }
          stf(out, (t*NN + i)*2 + lane, a, isf32);
        }
        if (!last) {
          lstm_prep(F, nnorm, isf32, t + 1, i, tid, wave, lane,
                    wih_r, whh_r, bih_r, s_win, s_cB,
                    s_x, s_hc, s_cc, s_gates, s_h1, s_cw, s_og, s_u1, &s_s1);
        } else {
          // ---- finalize: own-row h/c + (block 0) scalars via bypass readback
          if (wave == 0) stf(out, T_STEPS*NN*2 + i*DH + lane,         s_hc[lane], isf32);
          if (wave == 1) stf(out, T_STEPS*NN*2 + NN*DH + i*DH + lane, s_cc[lane], isf32);
          if (i == 0) {
            if (tid < NSTEP*4) s_fin[tid] = ld_coh_f32(F + O_ACC + tid);
            __syncthreads();
            if (tid == 0) {
              float v1 = 0.f, v2 = 0.f, v3 = 0.f;
              for (int tt = 0; tt < NSTEP; tt++) {
                float sg = s_fin[tt*4 + 0], sn = s_fin[tt*4 + 1];
                float sp = s_fin[tt*4 + 2], sm = s_fin[tt*4 + 3];
                v1 += sg / (sn * 64.f + 1e-6f);
                v2 += sp / (sm + 1e-6f);
                v3 += sn / 192.f;
              }
              int base = T_STEPS*NN*2 + 2*NN*DH;
              stf(out, base + 0, v1 / 20.f, isf32);
              stf(out, base + 1, v2 / 20.f, isf32);
              stf(out, base + 2, v3 / 20.f, isf32);
            }
          }
        }
      }
    }
  }
}

extern "C" void kernel_launch(void* const* d_in, const int* in_sizes, int n_in,
                              void* d_out, int out_size, void* d_ws, size_t ws_size,
                              hipStream_t stream) {
  const void* nabs  = d_in[0];
  const void* nnorm = d_in[1];
  const int* seq = (const int*)d_in[18];
  const int* nei = (const int*)d_in[19];
  float* F = (float*)d_ws;

  // host-side dtype hint from w_gate byte size (2*64*160 elements)
  int isf = -1;
  if (n_in > 11 && in_sizes) {
    if      (in_sizes[11] == 81920) isf = 1;
    else if (in_sizes[11] == 40960) isf = 0;
  }

  k_init<<<NN, 256, 0, stream>>>(F, d_out,
      d_in[3], d_in[4], d_in[5], d_in[6], d_in[7], d_in[8], d_in[9], d_in[10],
      d_in[11], d_in[12], d_in[13], d_in[14], d_in[15], d_in[16], d_in[17], isf);
  k_main<<<NN, 256, 0, stream>>>(F, nabs, nnorm, seq, nei, d_out, isf);
}

// Round 8
// 1168.764 us; speedup vs baseline: 1.1087x; 1.1087x over previous
//
#include <hip/hip_runtime.h>
#include <hip/hip_bf16.h>

#define T_STEPS 20
#define NSTEP   19
#define NN      192
#define DH      64
#define DE      32

// ---------------- workspace float offsets ----------------
enum : int {
  O_H     = 0,                 // (unused; layout kept)
  O_C     = O_H    + NN*DH,
  O_UH0   = O_C    + NN*DH,    // [N][64] float2 {U20, HW0}  — BYPASS-ONLY access
  O_UH1   = O_UH0  + 2*NN*DH,  // [N][64] float2 {U21, HW1}  — BYPASS-ONLY access
  O_CW    = O_UH1  + 2*NN*DH,  // (unused)
  O_OG    = O_CW   + NN*DH,    // (unused)
  O_U1    = O_OG   + NN*DH,    // (unused)
  O_S1    = O_U1   + NN*DH,    // (unused)
  O_S20   = O_S1   + NN,       // BYPASS-ONLY
  O_S21   = O_S20  + NN,       // BYPASS-ONLY
  O_ACC   = O_S21  + NN,       // [19][4] atomics; bypass readback at finalize
  O_FLAGA = O_ACC  + NSTEP*4,  // [192] arrival flags, 16-float padded
  O_FLAGR = O_FLAGA+ NN*16,    // [192] release flags, 16-float padded
  O_WIHT  = O_FLAGR+ NN*16,    // [e][G] 8192  (zero region ends here)
  O_WHHT  = O_WIHT + 8192,     // [k][G] 16384
  O_BIH   = O_WHHT + 16384,
  O_WIN   = O_BIH  + 256,
  O_BIN   = O_WIN  + 64,
  O_WRELF = O_BIN  + 32,       // 128  [p][d][c]
  O_BRELF = O_WRELF+ 128,
  O_WGR   = O_BRELF+ 64,       // 4096 [p][d][h]  (transposed)
  O_WGH1T = O_WGR  + 4096,     // 8192 [p][k][h]
  O_WGH2T = O_WGH1T+ 8192,
  O_BGATE = O_WGH2T+ 8192,     // contiguous small-const region cB:
  O_WARR  = O_BGATE+ 128,      //   BGATE 128, WARR 64, WARH1 128, WARH2 128, BAR 4
  O_WARH1 = O_WARR + 64,
  O_WARH2 = O_WARH1+ 128,
  O_BAR   = O_WARH2+ 128,
  O_WNEIT = O_BAR  + 4,        // 8192 [p][k][h]
  O_WOUT  = O_WNEIT+ 8192,     // cC: WOUT 128, BOUT 2
  O_BOUT  = O_WOUT + 128,
  O_ISF   = O_BOUT + 2,
  O_TOTAL = O_ISF  + 1
};

typedef unsigned long long ull;

__device__ __forceinline__ float bf2f(__hip_bfloat16 v) { return __bfloat162float(v); }
__device__ __forceinline__ float sigm(float x) { return 1.0f / (1.0f + __expf(-x)); }
__device__ __forceinline__ float tanh_fast(float x) {
  float e = __expf(-2.0f * fabsf(x));
  float r = (1.0f - e) / (1.0f + e);
  return copysignf(r, x);
}

__device__ __forceinline__ float ldf(const void* p, int idx, int isf32) {
  if (isf32) return ((const float*)p)[idx];
  return bf2f(((const __hip_bfloat16*)p)[idx]);
}
__device__ __forceinline__ void stf(void* p, int idx, float v, int isf32) {
  if (isf32) ((float*)p)[idx] = v;
  else       ((__hip_bfloat16*)p)[idx] = __float2bfloat16(v);
}

// -------- cache-bypass (sc0 sc1) plain loads/stores: coherent at the device
// coherence point, never allocate/consult L1/L2 (proven correct R7).
__device__ __forceinline__ ull ld_coh_u64_async(const void* p) {
  ull v;
  asm volatile("global_load_dwordx2 %0, %1, off sc0 sc1" : "=v"(v) : "v"(p));
  return v;
}
__device__ __forceinline__ float ld_coh_f32_async(const void* p) {
  float v;
  asm volatile("global_load_dword %0, %1, off sc0 sc1" : "=v"(v) : "v"(p));
  return v;
}
__device__ __forceinline__ float ld_coh_f32(const void* p) {   // completed
  float v;
  asm volatile("global_load_dword %0, %1, off sc0 sc1\n\ts_waitcnt vmcnt(0)"
               : "=v"(v) : "v"(p) : "memory");
  return v;
}
__device__ __forceinline__ unsigned ld_coh_u32(const void* p) { // completed
  unsigned v;
  asm volatile("global_load_dword %0, %1, off sc0 sc1\n\ts_waitcnt vmcnt(0)"
               : "=v"(v) : "v"(p) : "memory");
  return v;
}
__device__ __forceinline__ void st_coh_f32(void* p, float v) {
  asm volatile("global_store_dword %0, %1, off sc0 sc1" :: "v"(p), "v"(v) : "memory");
}
__device__ __forceinline__ void st_coh_u32(void* p, unsigned v) {
  asm volatile("global_store_dword %0, %1, off sc0 sc1" :: "v"(p), "v"(v) : "memory");
}
__device__ __forceinline__ void vm_wait0() {
  asm volatile("s_waitcnt vmcnt(0)" ::: "memory");
  __builtin_amdgcn_sched_barrier(0);
}

// Contention-free fence-free grid barrier.
// Arrival: each block stores its OWN padded flag (192 parallel stores, no
// shared-line RMW). Detect: block0's 192 threads poll 192 DISTINCT lines in
// parallel. Release: block0's 192 threads write 192 per-block release words;
// each block polls only ITS OWN word. Monotone epochs, no reset, no ABA.
// Coherence via sc0sc1 ops at the device coherence point (proven R7).
__device__ __forceinline__ void gridbar(float* F, unsigned ep, int i, int tid) {
  asm volatile("s_waitcnt vmcnt(0)" ::: "memory");  // my bypass stores complete
  __syncthreads();
  unsigned* flagA = (unsigned*)(F + O_FLAGA);
  unsigned* flagR = (unsigned*)(F + O_FLAGR);
  const unsigned tgt = ep + 1u;
  if (tid == 0) st_coh_u32(flagA + i*16, tgt);      // arrive (own line)
  if (i == 0) {
    if (tid < NN) {                                 // parallel scan, own line each
      while (ld_coh_u32(flagA + tid*16) < tgt) __builtin_amdgcn_s_sleep(2);
    }
    __syncthreads();                                // all arrivals observed
    if (tid < NN) st_coh_u32(flagR + tid*16, tgt);  // parallel per-block release
  } else {
    if (tid == 0) {                                 // poll own release word only
      while (ld_coh_u32(flagR + i*16) < tgt) __builtin_amdgcn_s_sleep(1);
    }
  }
  __syncthreads();
}

// ---------------- init: detect dtype, zero state, convert/transpose weights ----
__global__ __launch_bounds__(256) void k_init(float* __restrict__ F,
                       void* __restrict__ out,
                       const void* w_in,  const void* b_in,
                       const void* w_ih,  const void* w_hh,
                       const void* b_ih,  const void* b_hh,
                       const void* w_rel, const void* b_rel,
                       const void* w_gate,const void* b_gate,
                       const void* w_ar,  const void* b_ar,
                       const void* w_nei, const void* w_out,
                       const void* b_out, int isf_arg) {
  __shared__ int s_isf;
  const int wave = threadIdx.x >> 6, lane = threadIdx.x & 63;
  if (isf_arg >= 0) {
    if (threadIdx.x == 0) s_isf = isf_arg;
  } else if (wave == 0) {
    // dtype detect fallback (proven r3-r9)
    const unsigned short* u = (const unsigned short*)w_gate;
    int bad = 0;
    for (int x = lane; x < 1024; x += 64) {
      float v = __uint_as_float(((unsigned)u[x]) << 16);
      if (!(fabsf(v) <= 4.0f)) bad++;
    }
    for (int o = 32; o >= 1; o >>= 1) bad += __shfl_xor(bad, o, 64);
    if (lane == 0) s_isf = (bad > 64);
  }
  __syncthreads();
  const int isf32 = s_isf;
  if (blockIdx.x == 0 && threadIdx.x == 0) F[O_ISF] = (float)isf32;

  int tid = blockIdx.x * blockDim.x + threadIdx.x;
  int stride = gridDim.x * blockDim.x;
  for (int x = tid; x < O_WIHT; x += stride) F[x] = 0.f;   // incl. UH/S2/ACC/FLAGS
  for (int x = tid; x < NN*2;  x += stride) stf(out, (T_STEPS-1)*NN*2 + x, 0.f, isf32);
  for (int x = tid; x < 8192;  x += stride) { int e = x >> 8, G = x & 255; F[O_WIHT + x] = ldf(w_ih, G*32 + e, isf32); }
  for (int x = tid; x < 16384; x += stride) { int k = x >> 8, G = x & 255; F[O_WHHT + x] = ldf(w_hh, G*64 + k, isf32); }
  for (int x = tid; x < 256;   x += stride) F[O_BIH + x] = ldf(b_ih, x, isf32) + ldf(b_hh, x, isf32);
  for (int x = tid; x < 64;    x += stride) F[O_WIN + x] = ldf(w_in, x, isf32);
  for (int x = tid; x < 32;    x += stride) F[O_BIN + x] = ldf(b_in, x, isf32);
  for (int x = tid; x < 128;   x += stride) F[O_WRELF + x] = ldf(w_rel, x, isf32);
  for (int x = tid; x < 64;    x += stride) F[O_BRELF + x] = ldf(b_rel, x, isf32);
  // WGR transposed [p][d][h]
  for (int x = tid; x < 4096;  x += stride) { int p = x >> 11, d = (x >> 6) & 31, h = x & 63;
    F[O_WGR + x] = ldf(w_gate, p*10240 + h*160 + d, isf32); }
  for (int x = tid; x < 8192;  x += stride) { int p = x >> 12, k = (x >> 6) & 63, h = x & 63;
    F[O_WGH1T + x] = ldf(w_gate, p*10240 + h*160 + 32 + k, isf32); }
  for (int x = tid; x < 8192;  x += stride) { int p = x >> 12, k = (x >> 6) & 63, h = x & 63;
    F[O_WGH2T + x] = ldf(w_gate, p*10240 + h*160 + 96 + k, isf32); }
  for (int x = tid; x < 128;   x += stride) F[O_BGATE + x] = ldf(b_gate, x, isf32);
  for (int x = tid; x < 64;    x += stride) { int p = x >> 5, d = x & 31; F[O_WARR + x] = ldf(w_ar, p*160 + d, isf32); }
  for (int x = tid; x < 128;   x += stride) { int p = x >> 6, k = x & 63; F[O_WARH1 + x] = ldf(w_ar, p*160 + 32 + k, isf32); }
  for (int x = tid; x < 128;   x += stride) { int p = x >> 6, k = x & 63; F[O_WARH2 + x] = ldf(w_ar, p*160 + 96 + k, isf32); }
  for (int x = tid; x < 2;     x += stride) F[O_BAR + x] = ldf(b_ar, x, isf32);
  for (int x = tid; x < 8192;  x += stride) { int p = x >> 12, k = (x >> 6) & 63, h = x & 63;
    F[O_WNEIT + x] = ldf(w_nei, p*4096 + h*64 + k, isf32); }
  for (int x = tid; x < 128;   x += stride) F[O_WOUT + x] = ldf(w_out, x, isf32);
  for (int x = tid; x < 2;     x += stride) F[O_BOUT + x] = ldf(b_out, x, isf32);
}

// LSTM step t + prep for gcn p=0 (R7-identical)
__device__ __forceinline__ void lstm_prep(
    float* __restrict__ F, const void* __restrict__ nnorm, int isf32,
    int t, int i, int tid, int wave, int lane,
    const float* wih_r, const float* whh_r, float bih_r,
    const float* s_win, const float* s_cB,
    float* s_x, float* s_hc, float* s_cc, float* s_gates, float* s_h1,
    float* s_cw, float* s_og, float* s_u1, float* s_s1)
{
  if (wave == 1 && lane < DE) {
    float nx = ldf(nnorm, (t*NN + i)*2 + 0, isf32);
    float ny = ldf(nnorm, (t*NN + i)*2 + 1, isf32);
    s_x[lane] = fmaxf(nx*s_win[lane*2] + ny*s_win[lane*2 + 1] + s_win[64 + lane], 0.f);
  }
  __syncthreads();
  {
    float acc = bih_r;                              // gate-major G = tid
#pragma unroll
    for (int e = 0; e < DE; e++) acc += wih_r[e] * s_x[e];
#pragma unroll
    for (int k = 0; k < DH; k++) acc += whh_r[k] * s_hc[k];
    s_gates[tid] = acc;
  }
  __syncthreads();
  if (wave == 0) {
    float ig = sigm(s_gates[lane]);
    float fg = sigm(s_gates[64 + lane]);
    float gg = tanh_fast(s_gates[128 + lane]);
    float og = sigm(s_gates[192 + lane]);
    float c1 = fg * s_cc[lane] + ig * gg;
    float h1 = og * tanh_fast(c1);
    s_cw[lane] = c1;
    s_og[lane] = og;
    s_h1[lane] = h1;
    st_coh_f32(F + O_UH0 + 2*(i*DH + lane) + 1, h1);   // publish HW0 (.y)
  }
  __syncthreads();
  if (wave == 0) {
    float a = 0.f;
    const float* w = F + O_WGH1T + lane;               // p=0, L2-hot
    for (int k = 0; k < DH; k++) a += w[k*DH] * s_h1[k];
    s_u1[lane] = a;
  } else if (wave == 1) {
    float a = 0.f;
    const float* w = F + O_WGH2T + lane;               // p=0, L2-hot
    for (int k = 0; k < DH; k++) a += w[k*DH] * s_h1[k];
    st_coh_f32(F + O_UH0 + 2*(i*DH + lane), a);        // publish U20 (.x)
  } else if (wave == 2) {
    float hp = s_h1[lane];
    float a1 = hp * s_cB[192 + lane];                  // WARH1 p=0
    float a2 = hp * s_cB[320 + lane];                  // WARH2 p=0
    for (int o = 32; o >= 1; o >>= 1) { a1 += __shfl_xor(a1, o, 64); a2 += __shfl_xor(a2, o, 64); }
    if (lane == 0) { *s_s1 = a1; st_coh_f32(F + O_S20 + i, a2); }
  }
}

// ---------------- persistent kernel: 19 steps, 2 fence-free barriers/step ---
__global__ __launch_bounds__(256, 1) void k_main(float* __restrict__ F,
    const void* __restrict__ nabs, const void* __restrict__ nnorm,
    const int* __restrict__ seq, const int* __restrict__ nei,
    void* __restrict__ out, int isf_arg)
{
  __shared__ float s_rt[NN*33];                    // 24.75 KB, pad-33
  __shared__ float s_score[NN], s_pos[NN], s_neif[NN];
  __shared__ int   s_jlist[NN];
  __shared__ ull   s_cmask[3];
  __shared__ float s_red[4*DH], s_v1[4], s_msg[DH], s_hprep[DH];
  __shared__ float s_x[DE], s_hc[DH], s_cc[DH], s_gates[4*DH], s_h1[DH];
  __shared__ float s_cw[DH], s_og[DH], s_u1[DH], s_s1;
  __shared__ float s_wgt[4096];                    // 16 KB  [p][d][h]
  __shared__ float s_cA[192], s_cB[452], s_cC[130], s_win[96];
  __shared__ float s_fin[NSTEP*4];

  const int tid = threadIdx.x, wave = tid >> 6, lane = tid & 63;
  const int i = blockIdx.x;
  const int isf32 = (isf_arg >= 0) ? isf_arg : (int)F[O_ISF];

  // one-time register caches (1 block/CU, VGPR budget huge)
  float wih_r[DE], whh_r[DH];
  const float bih_r = F[O_BIH + tid];
#pragma unroll
  for (int e = 0; e < DE; e++) wih_r[e] = F[O_WIHT + e*256 + tid];
#pragma unroll
  for (int k = 0; k < DH; k++) whh_r[k] = F[O_WHHT + k*256 + tid];

  // one-time LDS staging (weights/consts; no fences ever — stays valid)
  for (int x = tid; x < 4096; x += 256) s_wgt[x] = F[O_WGR + x];
  for (int x = tid; x < 192; x += 256) s_cA[x] = F[O_WRELF + x];
  for (int x = tid; x < 452; x += 256) s_cB[x] = F[O_BGATE + x];
  for (int x = tid; x < 130; x += 256) s_cC[x] = F[O_WOUT + x];
  for (int x = tid; x < 96;  x += 256) s_win[x] = F[O_WIN + x];
  if (wave == 0) { s_hc[lane] = 0.f; s_cc[lane] = 0.f; }
  __syncthreads();

  // t=0 LSTM (publishes UH0/S20 via bypass stores)
  lstm_prep(F, nnorm, isf32, 0, i, tid, wave, lane,
            wih_r, whh_r, bih_r, s_win, s_cB,
            s_x, s_hc, s_cc, s_gates, s_h1, s_cw, s_og, s_u1, &s_s1);

  unsigned ep = 0;
  for (int t = 0; t < NSTEP; ++t) {
    const int m_i = seq[t*NN + i] > 0;
    const int j = wave*64 + lane;

    // ---- masks + ballot j-list (pre-barrier; seq/nei only, shared by both passes)
    ull mymask = 0; int nf = 0;
    if (wave < 3) {
      nf = m_i && (seq[t*NN + j] > 0) && (nei[(t*NN + i)*NN + j] > 0);
      s_neif[j] = nf ? 1.f : 0.f;
      mymask = __ballot(nf != 0);
      if (lane == 0) s_cmask[wave] = mymask;
    }
    __syncthreads();
    const int c0 = __popcll(s_cmask[0]), c1 = __popcll(s_cmask[1]);
    const int nv = c0 + c1 + __popcll(s_cmask[2]);
    if (wave < 3 && nf) {
      int base = (wave == 0) ? 0 : ((wave == 1) ? c0 : c0 + c1);
      ull lt = (1ull << lane) - 1ull;
      s_jlist[base + __popcll(mymask & lt)] = j;
    }

    for (int p = 0; p < 2; ++p) {
      gridbar(F, ep++, i, tid);            // peers' UH/S2 at coherence point
      const int last = (t == NSTEP - 1) && (p == 1);
      const int UHr = p ? O_UH1 : O_UH0;
      const int S2r = p ? O_S21 : O_S20;

      // ---- P1: early async S2 bypass load, r values, raw scores
      if (wave < 3) {
        float s2j = ld_coh_f32_async(F + S2r + j);
        float sc = 0.f, dot = 0.f;
        if (nf) {
          float cx = ldf(nabs, (t*NN + i)*2 + 0, isf32) - ldf(nabs, (t*NN + j)*2 + 0, isf32);
          float cy = ldf(nabs, (t*NN + i)*2 + 1, isf32) - ldf(nabs, (t*NN + j)*2 + 1, isf32);
          const float* wr = s_cA + p*64;
          const float* br = s_cA + 128 + p*32;
          const float* wa = s_cB + 128 + p*32;           // WARR
#pragma unroll
          for (int d = 0; d < 32; d++) {
            float rv = fmaxf(cx*wr[2*d] + cy*wr[2*d+1] + br[d], 0.f);
            s_rt[j*33 + d] = rv;
            dot += rv * wa[d];
          }
        }
        vm_wait0();                                      // s2j landed
        if (nf) sc = dot + s_s1 + s2j + s_cB[448 + p];   // BAR
        s_score[j] = sc;
      }
      __syncthreads();

      // ---- P2: masked softmax + (p==0) row stats (wave 0)
      if (wave == 0) {
        float n0 = s_neif[lane], n1 = s_neif[64+lane], n2 = s_neif[128+lane];
        float sc0 = s_score[lane], sc1 = s_score[64+lane], sc2 = s_score[128+lane];
        const float NEG = -3.0e38f;
        float mx = fmaxf(fmaxf(n0 > 0.f ? sc0 : NEG, n1 > 0.f ? sc1 : NEG),
                         n2 > 0.f ? sc2 : NEG);
        for (int o = 32; o >= 1; o >>= 1) mx = fmaxf(mx, __shfl_xor(mx, o, 64));
        float e0 = (n0 > 0.f) ? __expf(sc0 - mx) : 0.f;
        float e1 = (n1 > 0.f) ? __expf(sc1 - mx) : 0.f;
        float e2 = (n2 > 0.f) ? __expf(sc2 - mx) : 0.f;
        float s = e0 + e1 + e2;
        for (int o = 32; o >= 1; o >>= 1) s += __shfl_xor(s, o, 64);
        float inv = (s > 0.f) ? 1.0f / s : 0.f;
        float p0 = e0*inv, p1 = e1*inv, p2 = e2*inv;
        s_pos[lane] = p0; s_pos[64+lane] = p1; s_pos[128+lane] = p2;
        if (p == 0 && m_i) {
          float cnt = n0 + n1 + n2;
          float pm  = fmaxf(fmaxf(p0, p1), p2);
          for (int o = 32; o >= 1; o >>= 1) {
            cnt += __shfl_xor(cnt, o, 64);
            pm   = fmaxf(pm, __shfl_xor(pm, o, 64));
          }
          if (lane == 0 && cnt > 0.f) {
            atomicAdd(&F[O_ACC + t*4 + 1], cnt);
            atomicAdd(&F[O_ACC + t*4 + 2], pm);
            atomicAdd(&F[O_ACC + t*4 + 3], 1.f);
          }
        }
      }
      __syncthreads();

      // ---- P3: gates + msg over compacted list; UH via chunked bypass gather
      {
        float msg = 0.f, v1 = 0.f;
        if (m_i && nv > 0) {
          float wreg[32];
#pragma unroll
          for (int d = 0; d < 32; d++) wreg[d] = s_wgt[p*2048 + d*64 + lane];
          float basev = s_u1[lane] + s_cB[p*DH + lane];  // BGATE
          const float* UHbase = F + UHr;
          for (int c = 0; c < 6; ++c) {
            int k0 = wave + c*32;                        // kk = k0 + 4m, m<8
            if (k0 >= nv) break;
            int jv[8]; ull u[8];
#pragma unroll
            for (int m = 0; m < 8; m++) {
              int kk = k0 + 4*m;
              jv[m] = (kk < nv) ? s_jlist[kk] : 0;
              u[m] = ld_coh_u64_async(UHbase + 2*(jv[m]*DH + lane));
            }
            vm_wait0();
#pragma unroll
            for (int m = 0; m < 8; m++) {
              int kk = k0 + 4*m;
              if (kk < nv) {
                float ux = __uint_as_float((unsigned)u[m]);
                float uy = __uint_as_float((unsigned)(u[m] >> 32));
                float acc = basev + ux;
                const float* rr = &s_rt[jv[m]*33];
#pragma unroll
                for (int d = 0; d < 32; d++) acc += rr[d] * wreg[d];
                float g = sigm(acc);
                v1 += g;
                msg += s_pos[jv[m]] * g * uy;
              }
            }
          }
        }
        s_red[wave*DH + lane] = msg;
        for (int o = 32; o >= 1; o >>= 1) v1 += __shfl_xor(v1, o, 64);
        if (lane == 0) s_v1[wave] = v1;
      }
      __syncthreads();

      // ---- T1: combine partials + v1 atomic (wave 0)
      if (wave == 0) {
        s_msg[lane] = s_red[lane] + s_red[64+lane] + s_red[128+lane] + s_red[192+lane];
        if (p == 0 && m_i && lane == 0) {
          atomicAdd(&F[O_ACC + t*4 + 0], s_v1[0] + s_v1[1] + s_v1[2] + s_v1[3]);
        }
      }
      __syncthreads();

      // ---- T2: c/h update; publish (p=0) or commit-to-LDS (p=1)
      if (wave == 0) {
        float hcom, ccom = 0.f;
        if (m_i) {
          float cn = s_cw[lane];
          const float* wn = F + O_WNEIT + p*4096 + lane;  // L2-hot
          for (int k = 0; k < DH; k++) cn += s_msg[k] * wn[k*DH];
          hcom = s_og[lane] * tanh_fast(cn);
          s_cw[lane] = cn;
          ccom = cn;
        } else {
          hcom = p ? s_hprep[lane] : s_h1[lane];   // gcn identity for masked
        }
        if (p == 0) st_coh_f32(F + O_UH1 + 2*(i*DH + lane) + 1, hcom); // HW1
        s_hprep[lane] = hcom;
        if (p == 1 && m_i) { s_hc[lane] = hcom; s_cc[lane] = ccom; }
      }
      __syncthreads();

      if (p == 0) {
        // ---- PREP for p=1 from post-gcn0 h
        if (wave == 0) {
          float a = 0.f;
          const float* w = F + O_WGH1T + 4096 + lane;     // p=1, L2-hot
          for (int k = 0; k < DH; k++) a += w[k*DH] * s_hprep[k];
          s_u1[lane] = a;
        } else if (wave == 1) {
          float a = 0.f;
          const float* w = F + O_WGH2T + 4096 + lane;     // p=1, L2-hot
          for (int k = 0; k < DH; k++) a += w[k*DH] * s_hprep[k];
          st_coh_f32(F + O_UH1 + 2*(i*DH + lane), a);     // publish U21 (.x)
        } else if (wave == 2) {
          float hp = s_hprep[lane];
          float a1 = hp * s_cB[192 + DH + lane];          // WARH1 p=1
          float a2 = hp * s_cB[320 + DH + lane];          // WARH2 p=1
          for (int o = 32; o >= 1; o >>= 1) { a1 += __shfl_xor(a1, o, 64); a2 += __shfl_xor(a2, o, 64); }
          if (lane == 0) { s_s1 = a1; st_coh_f32(F + O_S21 + i, a2); }
        }
      } else {
        // ---- OUT row for step t
        if (wave == 0 && lane < 2) {
          float a = 0.f;
          if (m_i) {
            a = s_cC[128 + lane];                         // BOUT
            const float* wo = s_cC + lane*DH;             // WOUT
            for (int h = 0; h < DH; h++) a += s_hprep[h] * wo[h];
          }
          stf(out, (t*NN + i)*2 + lane, a, isf32);
        }
        if (!last) {
          lstm_prep(F, nnorm, isf32, t + 1, i, tid, wave, lane,
                    wih_r, whh_r, bih_r, s_win, s_cB,
                    s_x, s_hc, s_cc, s_gates, s_h1, s_cw, s_og, s_u1, &s_s1);
        } else {
          // ---- finalize: own-row h/c + (block 0) scalars via bypass readback
          if (wave == 0) stf(out, T_STEPS*NN*2 + i*DH + lane,         s_hc[lane], isf32);
          if (wave == 1) stf(out, T_STEPS*NN*2 + NN*DH + i*DH + lane, s_cc[lane], isf32);
          if (i == 0) {
            if (tid < NSTEP*4) s_fin[tid] = ld_coh_f32(F + O_ACC + tid);
            __syncthreads();
            if (tid == 0) {
              float v1 = 0.f, v2 = 0.f, v3 = 0.f;
              for (int tt = 0; tt < NSTEP; tt++) {
                float sg = s_fin[tt*4 + 0], sn = s_fin[tt*4 + 1];
                float sp = s_fin[tt*4 + 2], sm = s_fin[tt*4 + 3];
                v1 += sg / (sn * 64.f + 1e-6f);
                v2 += sp / (sm + 1e-6f);
                v3 += sn / 192.f;
              }
              int base = T_STEPS*NN*2 + 2*NN*DH;
              stf(out, base + 0, v1 / 20.f, isf32);
              stf(out, base + 1, v2 / 20.f, isf32);
              stf(out, base + 2, v3 / 20.f, isf32);
            }
          }
        }
      }
    }
  }
}

extern "C" void kernel_launch(void* const* d_in, const int* in_sizes, int n_in,
                              void* d_out, int out_size, void* d_ws, size_t ws_size,
                              hipStream_t stream) {
  const void* nabs  = d_in[0];
  const void* nnorm = d_in[1];
  const int* seq = (const int*)d_in[18];
  const int* nei = (const int*)d_in[19];
  float* F = (float*)d_ws;

  // host-side dtype hint from w_gate byte size (2*64*160 elements)
  int isf = -1;
  if (n_in > 11 && in_sizes) {
    if      (in_sizes[11] == 81920) isf = 1;
    else if (in_sizes[11] == 40960) isf = 0;
  }

  k_init<<<NN, 256, 0, stream>>>(F, d_out,
      d_in[3], d_in[4], d_in[5], d_in[6], d_in[7], d_in[8], d_in[9], d_in[10],
      d_in[11], d_in[12], d_in[13], d_in[14], d_in[15], d_in[16], d_in[17], isf);
  k_main<<<NN, 256, 0, stream>>>(F, nabs, nnorm, seq, nei, d_out, isf);
}